// Round 5
// baseline (1504.985 us; speedup 1.0000x reference)
//
#include <hip/hip_runtime.h>
#include <stdint.h>
#include <stddef.h>

typedef __attribute__((ext_vector_type(8))) short short8;
typedef __attribute__((ext_vector_type(8))) _Float16 half8;
typedef __attribute__((ext_vector_type(4))) float f32x4;
typedef unsigned long long ull;

#define T_  256
#define B_  256
#define C_  32
#define H_  512
#define O_  32
#define KB1 17
#define NT1 64
#define KB2 16
#define NT2 32

__device__ __forceinline__ short f2h(float f) {
  _Float16 h = (_Float16)f;
  return __builtin_bit_cast(short, h);
}
__device__ __forceinline__ void f2hl(float f, short& hi, short& lo) {
  _Float16 h = (_Float16)f;
  _Float16 l = (_Float16)(f - (float)h);
  hi = __builtin_bit_cast(short, h);
  lo = __builtin_bit_cast(short, l);
}
// pack value as {fp16 hi (low16), fp16 lo (high16)}
__device__ __forceinline__ unsigned int pack_hl(float f) {
  short h, l;
  f2hl(f, h, l);
  return (unsigned int)(unsigned short)h | ((unsigned int)(unsigned short)l << 16);
}
__device__ __forceinline__ float fast_tanh(float x) {
  float e = __expf(2.0f * x);
  return 1.0f - 2.0f / (e + 1.0f);
}
__device__ __forceinline__ float fast_sigmoid(float x) {
  return 1.0f / (1.0f + __expf(-x));
}
__device__ __forceinline__ f32x4 mfma16(half8 a, half8 b, f32x4 c) {
  return __builtin_amdgcn_mfma_f32_16x16x32_f16(a, b, c, 0, 0, 0);
}
__device__ __forceinline__ half8 ld8(const short* p) { return *(const half8*)p; }

// coherent (sc0 sc1) helpers — device-correct regardless of XCD placement
__device__ __forceinline__ void st_coh(unsigned int* p, unsigned int v) {
  __hip_atomic_store(p, v, __ATOMIC_RELAXED, __HIP_MEMORY_SCOPE_AGENT);
}
__device__ __forceinline__ ull ld_coh(const ull* p) {
  return __hip_atomic_load(p, __ATOMIC_RELAXED, __HIP_MEMORY_SCOPE_AGENT);
}

// stage 16 rows x 512 packed values (global, coherent) -> split hi/lo LDS planes.
// Pair-index p covers 4 packed cols (2 ull). Unpack = word merges + b64 writes.
__device__ __forceinline__ void stage_pl(const ull* src, short* hi, short* lo,
                                         int stride, int tid) {
  ull v[16];
  #pragma unroll
  for (int i = 0; i < 8; ++i) {
    int p = i * 256 + tid;
    v[2 * i]     = ld_coh(src + 2 * p);
    v[2 * i + 1] = ld_coh(src + 2 * p + 1);
  }
  #pragma unroll
  for (int i = 0; i < 8; ++i) {
    int p = i * 256 + tid;
    int row = p >> 7, col4 = (p & 127) << 2;
    unsigned int u0 = (unsigned int)v[2 * i],     u1 = (unsigned int)(v[2 * i] >> 32);
    unsigned int u2 = (unsigned int)v[2 * i + 1], u3 = (unsigned int)(v[2 * i + 1] >> 32);
    unsigned int hiA = (u0 & 0xffffu) | (u1 << 16);
    unsigned int hiB = (u2 & 0xffffu) | (u3 << 16);
    unsigned int loA = (u0 >> 16) | (u1 & 0xffff0000u);
    unsigned int loB = (u2 >> 16) | (u3 & 0xffff0000u);
    *(ull*)(hi + row * stride + col4) = (ull)hiA | ((ull)hiB << 32);
    *(ull*)(lo + row * stride + col4) = (ull)loA | ((ull)loB << 32);
  }
}

// bg-local barrier: monotonic counter, no threadfence (no L2 wb/inv).
__device__ __forceinline__ void bg_barrier(unsigned int* cnt, unsigned int target) {
  __syncthreads();
  if (threadIdx.x == 0) {
    __hip_atomic_fetch_add(cnt, 1u, __ATOMIC_RELAXED, __HIP_MEMORY_SCOPE_AGENT);
    while (__hip_atomic_load(cnt, __ATOMIC_RELAXED, __HIP_MEMORY_SCOPE_AGENT) < target)
      __builtin_amdgcn_s_sleep(1);
  }
  __syncthreads();
}

// ---------------- weight packing (layout unchanged) ----------------
__global__ void pack_b1s(const float* __restrict__ W1, const float* __restrict__ Wg,
                         short* __restrict__ hi, short* __restrict__ lo) {
  int gid = blockIdx.x * 256 + threadIdx.x;
  if (gid >= KB1 * NT1 * 512) return;
  int j = gid & 7, lane = (gid >> 3) & 63, tile = gid >> 9;
  int nt = tile % NT1, kb = tile / NT1;
  int k = kb * 32 + ((lane >> 4) << 3) + j;
  int n = ((nt & 31) << 4) + (lane & 15);
  float v = 0.f;
  if (nt < 32)      v = W1[k * H_ + n];
  else if (k < H_)  v = Wg[k * H_ + n];
  short h, l;
  f2hl(v, h, l);
  hi[gid] = h; lo[gid] = l;
}

__global__ void pack_s(const float* __restrict__ src, short* __restrict__ hi,
                       short* __restrict__ lo, int Ksrc, int Nsrc, int KB, int NT) {
  int gid = blockIdx.x * 256 + threadIdx.x;
  if (gid >= KB * NT * 512) return;
  int j = gid & 7, lane = (gid >> 3) & 63, tile = gid >> 9;
  int nt = tile % NT, kb = tile / NT;
  int k = kb * 32 + ((lane >> 4) << 3) + j;
  int n = (nt << 4) + (lane & 15);
  float v = (k < Ksrc && n < Nsrc) ? src[k * Nsrc + n] : 0.f;
  short h, l;
  f2hl(v, h, l);
  hi[gid] = h;
  if (lo) lo[gid] = l;
}

// ---------------- SDE scan: 256 WGs (16 bg x 16 cg), weights in registers ----
__global__ __launch_bounds__(256, 1) void sde_kernel(
    const float* __restrict__ times, const float* __restrict__ coeffs,
    const float* __restrict__ dW,
    const float* __restrict__ b_init, const float* __restrict__ b1,
    const float* __restrict__ b2, const float* __restrict__ bgb,
    const short* __restrict__ B1h, const short* __restrict__ B1l,
    const short* __restrict__ W2h, const short* __restrict__ W2l,
    const short* __restrict__ WIh, const short* __restrict__ WIl,
    unsigned int* __restrict__ y_pk, unsigned int* __restrict__ h_pk,
    short* __restrict__ zt, unsigned int* __restrict__ cnt_base) {
  __shared__ short yx_hi[16][552];
  __shared__ short yx_lo[16][552];
  __shared__ short hh_hi[16][520];
  __shared__ short hh_lo[16][520];
  __shared__ float g_x[16][32];
  __shared__ float redbuf[4];

  const int tid = threadIdx.x;
  const int w = tid >> 6, l = tid & 63;
  const int ra = l & 15, kq = l >> 4;
  const int bid = blockIdx.x;
  const int bg = bid & 15, cg = bid >> 4;
  const int R0 = bg << 4;
  unsigned int* cnt = cnt_base + bg * 32;

  const int nt1w = (w < 2) ? (2 * cg + w) : (32 + 2 * cg + (w - 2));
  const int extcol = nt1w * 16 + ra;
  const int ntF = 2 * cg + (w & 1);
  const int fcol = ntF * 16 + ra;

  float d = 1e30f;
  if (tid < T_ - 1) d = times[tid + 1] - times[tid];
  #pragma unroll
  for (int s = 32; s >= 1; s >>= 1) d = fminf(d, __shfl_xor(d, s, 64));
  if (l == 0) redbuf[w] = d;

  // weight slices -> registers (held for all 255 steps)
  half8 wb1h[17], wb1l[17];
  #pragma unroll
  for (int kb = 0; kb < 17; ++kb) {
    const size_t off = ((size_t)(kb * 64 + nt1w) << 9) + (l << 3);
    wb1h[kb] = ld8(B1h + off);
    wb1l[kb] = ld8(B1l + off);
  }
  half8 ww2h[16], ww2l[16];
  if (w < 2) {
    #pragma unroll
    for (int kb = 0; kb < 16; ++kb) {
      const size_t off = ((size_t)(kb * 32 + ntF) << 9) + (l << 3);
      ww2h[kb] = ld8(W2h + off);
      ww2l[kb] = ld8(W2l + off);
    }
  }

  // stage x0
  if (tid < 64) {
    int row = tid >> 2, cc = (tid & 3) << 3;
    const float* xb = coeffs + (size_t)(R0 + row) * (T_ * C_) + cc;
    short8 hi, lo;
    #pragma unroll
    for (int j = 0; j < 8; ++j) {
      short h, l2;
      f2hl(xb[j], h, l2);
      hi[j] = h; lo[j] = l2;
    }
    *(short8*)&yx_hi[row][512 + cc] = hi;
    *(short8*)&yx_lo[row][512 + cc] = lo;
  }
  __syncthreads();
  float m = fminf(fminf(redbuf[0], redbuf[1]), fminf(redbuf[2], redbuf[3]));
  const float dt = fmaxf(m, 0.001f);
  const float sq = sqrtf(dt);

  const float b1v = (w < 2) ? b1[extcol] : 0.f;
  const float bgv = (w >= 2) ? bgb[extcol - 512] : 0.f;
  const float b2v = (w < 2) ? b2[fcol] : 0.f;

  // z0 = x0 @ W_init + b_init (waves 0/1 own cols)
  float yr[4] = {0.f, 0.f, 0.f, 0.f};
  if (w < 2) {
    half8 ah = ld8(&yx_hi[ra][512 + (kq << 3)]);
    half8 al = ld8(&yx_lo[ra][512 + (kq << 3)]);
    half8 bh = ld8(WIh + ((size_t)ntF << 9) + (l << 3));
    half8 bl = ld8(WIl + ((size_t)ntF << 9) + (l << 3));
    f32x4 Z = {0.f, 0.f, 0.f, 0.f};
    Z = mfma16(ah, bh, Z); Z = mfma16(al, bh, Z); Z = mfma16(ah, bl, Z);
    float bi = b_init[fcol];
    #pragma unroll
    for (int r = 0; r < 4; ++r) {
      yr[r] = Z[r] + bi;
      st_coh(&y_pk[(size_t)(R0 + (kq << 2) + r) * H_ + fcol], pack_hl(yr[r]));
    }
  }
  bg_barrier(cnt, 16u);

  // ---- main scan ----
  for (int k = 0; k < T_ - 1; ++k) {
    float dwv[4];
    if (w < 2) {
      const float* dwb = dW + ((size_t)k * B_ + R0) * H_ + fcol;
      #pragma unroll
      for (int r = 0; r < 4; ++r)
        dwv[r] = __builtin_nontemporal_load(dwb + ((kq << 2) + r) * H_);
    }
    // stage y (packed planes -> hi/lo LDS)
    stage_pl((const ull*)y_pk + R0 * 256, &yx_hi[0][0], &yx_lo[0][0], 552, tid);
    __syncthreads();
    // GEMM1: 3-term split-fp16, 3 independent accumulator chains
    f32x4 Aa = {0.f, 0.f, 0.f, 0.f}, Ab = Aa, Ac = Aa;
    #pragma unroll
    for (int kb = 0; kb < 17; ++kb) {
      half8 ah = ld8(&yx_hi[ra][(kb << 5) + (kq << 3)]);
      half8 al = ld8(&yx_lo[ra][(kb << 5) + (kq << 3)]);
      Aa = mfma16(ah, wb1h[kb], Aa);
      Ab = mfma16(al, wb1h[kb], Ab);
      Ac = mfma16(ah, wb1l[kb], Ac);
    }
    if (w < 2) {
      #pragma unroll
      for (int r = 0; r < 4; ++r) {
        float h = fast_tanh((Aa[r] + Ab[r]) + Ac[r] + b1v);
        st_coh(&h_pk[(size_t)(R0 + (kq << 2) + r) * H_ + extcol], pack_hl(h));
      }
    } else {
      #pragma unroll
      for (int r = 0; r < 4; ++r)
        g_x[(kq << 2) + r][((w - 2) << 4) + ra] =
            fast_sigmoid((Aa[r] + Ab[r]) + Ac[r] + bgv);
    }
    bg_barrier(cnt, 16u * (2u * (unsigned)k + 2u));
    // stage h (packed planes)
    stage_pl((const ull*)h_pk + R0 * 256, &hh_hi[0][0], &hh_lo[0][0], 520, tid);
    __syncthreads();
    if (w < 2) {
      // phase B: f = tanh(h @ W2 + b2), 3 chains
      f32x4 Fa = {0.f, 0.f, 0.f, 0.f}, Fb = Fa, Fc = Fa;
      #pragma unroll
      for (int kb = 0; kb < 16; ++kb) {
        half8 ah = ld8(&hh_hi[ra][(kb << 5) + (kq << 3)]);
        half8 al = ld8(&hh_lo[ra][(kb << 5) + (kq << 3)]);
        Fa = mfma16(ah, ww2h[kb], Fa);
        Fb = mfma16(al, ww2h[kb], Fb);
        Fc = mfma16(ah, ww2l[kb], Fc);
      }
      #pragma unroll
      for (int r = 0; r < 4; ++r) {
        float f = fast_tanh((Fa[r] + Fb[r]) + Fc[r] + b2v);
        float g = g_x[(kq << 2) + r][((w & 1) << 4) + ra];
        yr[r] += f * dt + g * (sq * dwv[r]);
        st_coh(&y_pk[(size_t)(R0 + (kq << 2) + r) * H_ + fcol], pack_hl(yr[r]));
      }
      if (k >= T_ - 1 - O_) {
        int t = k - (T_ - 1 - O_);
        #pragma unroll
        for (int r = 0; r < 4; ++r)
          zt[((size_t)(R0 + (kq << 2) + r) * O_ + t) * H_ + fcol] = f2h(yr[r]);
      }
    } else if (w == 2 && k < T_ - 2) {
      // stage x_{k+1} into yx (off critical path; GEMM1 readers of x_k are done)
      int row = l >> 2, cc = (l & 3) << 3;
      const float* xb =
          coeffs + (size_t)(R0 + row) * (T_ * C_) + (size_t)(k + 1) * C_ + cc;
      short8 hi, lo;
      #pragma unroll
      for (int j = 0; j < 8; ++j) {
        short h, l2;
        f2hl(xb[j], h, l2);
        hi[j] = h; lo[j] = l2;
      }
      *(short8*)&yx_hi[row][512 + cc] = hi;
      *(short8*)&yx_lo[row][512 + cc] = lo;
    }
    bg_barrier(cnt, 16u * (2u * (unsigned)k + 3u));
  }
}

// ---------------- head kernel (unchanged) ----------------
__global__ __launch_bounds__(256) void head_kernel(
    const short* __restrict__ zt, const short* __restrict__ Wh1p,
    const short* __restrict__ Wh2p, const float* __restrict__ bh1,
    const float* __restrict__ bh2, float* __restrict__ out) {
  __shared__ short a_lds[32][520];
  __shared__ short h2_lds[32][520];
  const int tid = threadIdx.x;
  const int w = tid >> 6, l = tid & 63;
  const int ra = l & 15, kq = l >> 4;
  const int r0 = blockIdx.x << 5;

  const short* zb = zt + (size_t)r0 * H_;
  #pragma unroll
  for (int i = 0; i < 8; ++i) {
    int cidx = i * 256 + tid;
    int row = cidx >> 6, cc = (cidx & 63) << 3;
    *(short8*)&a_lds[row][cc] = *(const short8*)(zb + row * H_ + cc);
  }
  __syncthreads();

  f32x4 acc[2][8];
  #pragma unroll
  for (int mt = 0; mt < 2; ++mt)
    #pragma unroll
    for (int i = 0; i < 8; ++i) acc[mt][i] = (f32x4){0.f, 0.f, 0.f, 0.f};
  for (int kb = 0; kb < 16; ++kb) {
    half8 a0 = ld8(&a_lds[ra][(kb << 5) + (kq << 3)]);
    half8 a1 = ld8(&a_lds[16 + ra][(kb << 5) + (kq << 3)]);
    const short* bp = Wh1p + (size_t)kb * (32 * 512) + (l << 3);
    #pragma unroll
    for (int i = 0; i < 8; ++i) {
      half8 b = ld8(bp + ((8 * w + i) << 9));
      acc[0][i] = mfma16(a0, b, acc[0][i]);
      acc[1][i] = mfma16(a1, b, acc[1][i]);
    }
  }
  #pragma unroll
  for (int i = 0; i < 8; ++i) {
    int col = ((8 * w + i) << 4) + ra;
    float bb = bh1[col];
    #pragma unroll
    for (int mt = 0; mt < 2; ++mt)
      #pragma unroll
      for (int r = 0; r < 4; ++r) {
        float h = acc[mt][i][r] + bb;
        h = h > 0.f ? h : 0.f;
        h2_lds[(mt << 4) + (kq << 2) + r][col] = f2h(h);
      }
  }
  __syncthreads();

  {
    int mt = w >> 1, nt = w & 1;
    f32x4 F = {0.f, 0.f, 0.f, 0.f};
    for (int kb = 0; kb < 16; ++kb) {
      half8 a = ld8(&h2_lds[(mt << 4) + ra][(kb << 5) + (kq << 3)]);
      half8 b = ld8(Wh2p + (size_t)((kb * 2 + nt) * 64 + l) * 8);
      F = mfma16(a, b, F);
    }
    int col = (nt << 4) + ra;
    float bb = bh2[col];
    #pragma unroll
    for (int r = 0; r < 4; ++r)
      out[(size_t)(r0 + (mt << 4) + (kq << 2) + r) * O_ + col] = F[r] + bb;
  }
}

// ---------------- launcher ----------------
extern "C" void kernel_launch(void* const* d_in, const int* in_sizes, int n_in,
                              void* d_out, int out_size, void* d_ws, size_t ws_size,
                              hipStream_t stream) {
  (void)in_sizes; (void)n_in; (void)out_size; (void)ws_size;
  const float* times  = (const float*)d_in[0];
  const float* coeffs = (const float*)d_in[1];
  const float* dW     = (const float*)d_in[3];
  const float* W_init = (const float*)d_in[4];
  const float* b_init = (const float*)d_in[5];
  const float* W1     = (const float*)d_in[6];
  const float* b1     = (const float*)d_in[7];
  const float* W2     = (const float*)d_in[8];
  const float* b2     = (const float*)d_in[9];
  const float* Wg     = (const float*)d_in[10];
  const float* bg     = (const float*)d_in[11];
  const float* Wh1    = (const float*)d_in[12];
  const float* bh1    = (const float*)d_in[13];
  const float* Wh2    = (const float*)d_in[14];
  const float* bh2    = (const float*)d_in[15];
  float* out = (float*)d_out;
  char* ws = (char*)d_ws;

  short* B1h  = (short*)(ws + 0);          // 1,114,112
  short* B1l  = (short*)(ws + 1114112);    // 1,114,112
  short* W2h  = (short*)(ws + 2228224);    //   524,288
  short* W2l  = (short*)(ws + 2752512);    //   524,288
  short* WIh  = (short*)(ws + 3276800);    //    32,768
  short* WIl  = (short*)(ws + 3309568);    //    32,768
  short* Wh1p = (short*)(ws + 3342336);    //   524,288
  short* Wh2p = (short*)(ws + 3866624);    //    32,768
  unsigned int* y_pk = (unsigned int*)(ws + 3899392);  // 524,288
  unsigned int* h_pk = (unsigned int*)(ws + 4423680);  // 524,288
  short* zt   = (short*)(ws + 4947968);    // 8,388,608
  unsigned int* cnt = (unsigned int*)(ws + 13336576);  // 2048

  pack_b1s<<<2176, 256, 0, stream>>>(W1, Wg, B1h, B1l);
  pack_s  <<<1024, 256, 0, stream>>>(W2, W2h, W2l, 512, 512, 16, 32);
  pack_s  <<<64,   256, 0, stream>>>(W_init, WIh, WIl, 32, 512, 1, 32);
  pack_s  <<<1024, 256, 0, stream>>>(Wh1, Wh1p, (short*)nullptr, 512, 512, 16, 32);
  pack_s  <<<64,   256, 0, stream>>>(Wh2, Wh2p, (short*)nullptr, 512, 32, 16, 2);

  hipMemsetAsync(ws + 13336576, 0, 2048, stream);

  sde_kernel<<<256, 256, 0, stream>>>(times, coeffs, dW, b_init, b1, b2, bg,
                                      B1h, B1l, W2h, W2l, WIh, WIl,
                                      y_pk, h_pk, zt, cnt);
  head_kernel<<<256, 256, 0, stream>>>(zt, Wh1p, Wh2p, bh1, bh2, out);
}